// Round 4
// baseline (2242.440 us; speedup 1.0000x reference)
//
#include <hip/hip_runtime.h>

#define DIM 128
#define N_USERS 200000
#define N_ITEMS 100000

typedef __attribute__((ext_vector_type(8))) _Float16 half8;
typedef __attribute__((ext_vector_type(4))) _Float16 half4v;
typedef __attribute__((ext_vector_type(4))) float f32x4;

// ===========================================================================
// CSR build: histogram -> 3-phase exclusive scan -> bucketed 2-stage scatter
// ===========================================================================

__global__ __launch_bounds__(256) void hist_kernel(
    const int* __restrict__ rows, int* __restrict__ counts, int nnz)
{
    int e = blockIdx.x * blockDim.x + threadIdx.x;
    if (e < nnz) atomicAdd(&counts[rows[e]], 1);
}

__global__ __launch_bounds__(256) void scan1_kernel(
    const int* __restrict__ in, int* __restrict__ out,
    int* __restrict__ blockSums, int n)
{
    __shared__ int lds[256];
    int tid  = threadIdx.x;
    int base = blockIdx.x * 1024 + tid * 4;
    int v0 = (base + 0 < n) ? in[base + 0] : 0;
    int v1 = (base + 1 < n) ? in[base + 1] : 0;
    int v2 = (base + 2 < n) ? in[base + 2] : 0;
    int v3 = (base + 3 < n) ? in[base + 3] : 0;
    int s1 = v0 + v1, s2 = s1 + v2, s3 = s2 + v3;
    lds[tid] = s3;
    __syncthreads();
    for (int d = 1; d < 256; d <<= 1) {
        int t = 0;
        if (tid >= d) t = lds[tid - d];
        __syncthreads();
        lds[tid] += t;
        __syncthreads();
    }
    int excl = (tid > 0) ? lds[tid - 1] : 0;
    if (base + 0 < n) out[base + 1] = excl + v0;
    if (base + 1 < n) out[base + 2] = excl + s1;
    if (base + 2 < n) out[base + 3] = excl + s2;
    if (base + 3 < n) out[base + 4] = excl + s3;
    if (tid == 255) blockSums[blockIdx.x] = lds[255];
    if (blockIdx.x == 0 && tid == 0) out[0] = 0;
}

__global__ __launch_bounds__(256) void scan2_kernel(int* __restrict__ bs, int nb)
{
    __shared__ int lds[256];
    int tid  = threadIdx.x;
    int base = tid * 4;
    int v0 = (base + 0 < nb) ? bs[base + 0] : 0;
    int v1 = (base + 1 < nb) ? bs[base + 1] : 0;
    int v2 = (base + 2 < nb) ? bs[base + 2] : 0;
    int v3 = (base + 3 < nb) ? bs[base + 3] : 0;
    int s1 = v0 + v1, s2 = s1 + v2, s3 = s2 + v3;
    lds[tid] = s3;
    __syncthreads();
    for (int d = 1; d < 256; d <<= 1) {
        int t = 0;
        if (tid >= d) t = lds[tid - d];
        __syncthreads();
        lds[tid] += t;
        __syncthreads();
    }
    int run = (tid > 0) ? lds[tid - 1] : 0;
    if (base + 0 < nb) { int o = bs[base + 0]; bs[base + 0] = run; run += o; }
    if (base + 1 < nb) { int o = bs[base + 1]; bs[base + 1] = run; run += o; }
    if (base + 2 < nb) { int o = bs[base + 2]; bs[base + 2] = run; run += o; }
    if (base + 3 < nb) { int o = bs[base + 3]; bs[base + 3] = run; run += o; }
}

__global__ __launch_bounds__(256) void scan3_kernel(
    int* __restrict__ out, const int* __restrict__ bs, int n)
{
    int b = blockIdx.x;
    if (b == 0) return;
    int add  = bs[b];
    int base = b * 1024 + threadIdx.x * 4;
    if (base + 0 < n) out[base + 1] += add;
    if (base + 1 < n) out[base + 2] += add;
    if (base + 2 < n) out[base + 3] += add;
    if (base + 3 < n) out[base + 4] += add;
}

// bcur[b] = off[min(b<<shift, n_rows)]
__global__ __launch_bounds__(256) void binit_kernel(
    const int* __restrict__ off, int* __restrict__ bcur,
    int n_rows, int shift, int nb)
{
    int b = blockIdx.x * blockDim.x + threadIdx.x;
    if (b >= nb) return;
    int r = b << shift;
    if (r > n_rows) r = n_rows;
    bcur[b] = off[r];
}

// Stage 1: append edge to its row-bucket region as packed u64
// rec = [ row_local : (31..18+shift unused) | col : 18 bits ] << 32 | val_bits
__global__ __launch_bounds__(256) void bucket_append_kernel(
    const int* __restrict__ rows, const int* __restrict__ cols,
    const float* __restrict__ vals, int* __restrict__ bcur,
    unsigned long long* __restrict__ staged, int nnz, int shift)
{
    int e = blockIdx.x * blockDim.x + threadIdx.x;
    if (e >= nnz) return;
    int r = rows[e];
    int b = r >> shift;
    int rl = r & ((1 << shift) - 1);
    int pos = atomicAdd(&bcur[b], 1);
    unsigned int hi = ((unsigned)rl << 18) | (unsigned)cols[e];
    unsigned long long rec =
        ((unsigned long long)hi << 32) | (unsigned)__float_as_uint(vals[e]);
    staged[pos] = rec;
}

// Stage 2: one block per bucket, scatter staged edges into final CSR slots
// (write window per bucket ~20-40 KB -> L2-resident)
__global__ __launch_bounds__(256) void bucket_scatter_kernel(
    const int* __restrict__ off, int* __restrict__ cursor,
    const unsigned long long* __restrict__ staged,
    int2* __restrict__ edges, int n_rows, int shift)
{
    int b    = blockIdx.x;
    int rbeg = b << shift;
    int rend = rbeg + (1 << shift);
    if (rend > n_rows) rend = n_rows;
    if (rbeg >= n_rows) return;
    int beg = off[rbeg], end = off[rend];
    for (int k = beg + threadIdx.x; k < end; k += blockDim.x) {
        unsigned long long rec = staged[k];
        unsigned int hi = (unsigned int)(rec >> 32);
        int col = (int)(hi & 0x3FFFF);
        int rl  = (int)(hi >> 18);
        int row = rbeg + rl;
        int pos = atomicAdd(&cursor[row], 1);
        edges[pos] = make_int2(col, (int)(unsigned int)(rec & 0xFFFFFFFFu));
    }
}

// ===========================================================================
// fp32 -> fp16 table conversion (8 elems / thread)
// ===========================================================================
__global__ __launch_bounds__(256) void conv_f16_kernel(
    const float* __restrict__ src, _Float16* __restrict__ dst, int n8)
{
    int t = blockIdx.x * blockDim.x + threadIdx.x;
    if (t >= n8) return;
    const float4* s = reinterpret_cast<const float4*>(src) + (size_t)t * 2;
    float4 a = s[0], b = s[1];
    half8 h;
    h[0] = (_Float16)a.x; h[1] = (_Float16)a.y;
    h[2] = (_Float16)a.z; h[3] = (_Float16)a.w;
    h[4] = (_Float16)b.x; h[5] = (_Float16)b.y;
    h[6] = (_Float16)b.z; h[7] = (_Float16)b.w;
    reinterpret_cast<half8*>(dst)[t] = h;
}

// W [2][256][128] fp32  ->  Wt [2][128][256] fp16 (transposed per layer)
__global__ __launch_bounds__(256) void transposeW_kernel(
    const float* __restrict__ W, _Float16* __restrict__ Wt)
{
    int t = blockIdx.x * blockDim.x + threadIdx.x;   // 0..65535
    int l = t >> 15;
    int r = t & 32767;
    int k = r >> 7;
    int n = r & 127;
    Wt[(size_t)l * 32768 + n * 256 + k] = (_Float16)W[t];
}

// ===========================================================================
// CSR SpMM fp16: 16 lanes/row, 16B gathers, 2-way unrolled for gather MLP,
// fp32 accum, fp16 store
// ===========================================================================
__global__ __launch_bounds__(256) void spmm_csr_f16_kernel(
    const int* __restrict__ off, const int2* __restrict__ edges,
    const _Float16* __restrict__ x, _Float16* __restrict__ out, int n_rows)
{
    int t    = blockIdx.x * blockDim.x + threadIdx.x;
    int row  = t >> 4;
    int lane = t & 15;
    if (row >= n_rows) return;
    int beg = off[row], end = off[row + 1];
    float acc[8] = {0.f, 0.f, 0.f, 0.f, 0.f, 0.f, 0.f, 0.f};
    int k = beg;
    for (; k + 1 < end; k += 2) {
        int2 e0 = edges[k];
        int2 e1 = edges[k + 1];
        half8 x0 = *reinterpret_cast<const half8*>(x + (size_t)e0.x * DIM + lane * 8);
        half8 x1 = *reinterpret_cast<const half8*>(x + (size_t)e1.x * DIM + lane * 8);
        float v0 = __int_as_float(e0.y);
        float v1 = __int_as_float(e1.y);
#pragma unroll
        for (int i = 0; i < 8; ++i) acc[i] += v0 * (float)x0[i];
#pragma unroll
        for (int i = 0; i < 8; ++i) acc[i] += v1 * (float)x1[i];
    }
    if (k < end) {
        int2 e0 = edges[k];
        half8 x0 = *reinterpret_cast<const half8*>(x + (size_t)e0.x * DIM + lane * 8);
        float v0 = __int_as_float(e0.y);
#pragma unroll
        for (int i = 0; i < 8; ++i) acc[i] += v0 * (float)x0[i];
    }
    half8 o;
#pragma unroll
    for (int i = 0; i < 8; ++i) o[i] = (_Float16)acc[i];
    *reinterpret_cast<half8*>(out + (size_t)row * DIM + lane * 8) = o;
}

// ===========================================================================
// MFMA GEMM: out = relu( concat([HO, CUR]) @ W + b ), fp16 in, fp32 acc.
// Swapped operands: mfma(Wt_frag, A_frag) -> each lane holds 4 consecutive
// output features of one row -> vectorized stores. Block 256 = 4 waves.
// ===========================================================================
template<int OUT_F32>
__global__ __launch_bounds__(256) void gemm_f16_kernel(
    const _Float16* __restrict__ HO, const _Float16* __restrict__ CUR,
    const _Float16* __restrict__ Wt,   // [128][256] fp16
    const float* __restrict__ bias,    // [128] fp32
    float* __restrict__ outF, _Float16* __restrict__ outH, int M)
{
    int tid  = threadIdx.x;
    int wave = tid >> 6;
    int l    = tid & 63;
    int m    = l & 15;
    int kg   = l >> 4;
    int row  = blockIdx.x * 64 + wave * 16 + m;
    int rr   = min(row, M - 1);

    half8 afrag[8];
#pragma unroll
    for (int kk = 0; kk < 8; ++kk) {
        const _Float16* src = (kk < 4) ? HO : CUR;
        int k0 = (kk & 3) * 32 + kg * 8;
        afrag[kk] = *reinterpret_cast<const half8*>(src + (size_t)rr * DIM + k0);
    }

#pragma unroll
    for (int j = 0; j < 8; ++j) {
        f32x4 acc = {0.f, 0.f, 0.f, 0.f};
#pragma unroll
        for (int kk = 0; kk < 8; ++kk) {
            half8 wfrag = *reinterpret_cast<const half8*>(
                Wt + (size_t)(j * 16 + m) * 256 + kk * 32 + kg * 8);
            acc = __builtin_amdgcn_mfma_f32_16x16x32_f16(wfrag, afrag[kk], acc, 0, 0, 0);
        }
        int n0 = j * 16 + kg * 4;
        float4 bv = *reinterpret_cast<const float4*>(bias + n0);
        float o0 = fmaxf(acc[0] + bv.x, 0.f);
        float o1 = fmaxf(acc[1] + bv.y, 0.f);
        float o2 = fmaxf(acc[2] + bv.z, 0.f);
        float o3 = fmaxf(acc[3] + bv.w, 0.f);
        if (row < M) {
            if (OUT_F32) {
                float4 st = make_float4(o0, o1, o2, o3);
                *reinterpret_cast<float4*>(outF + (size_t)row * DIM + n0) = st;
            } else {
                half4v st;
                st[0] = (_Float16)o0; st[1] = (_Float16)o1;
                st[2] = (_Float16)o2; st[3] = (_Float16)o3;
                *reinterpret_cast<half4v*>(outH + (size_t)row * DIM + n0) = st;
            }
        }
    }
}

extern "C" void kernel_launch(void* const* d_in, const int* in_sizes, int n_in,
                              void* d_out, int out_size, void* d_ws, size_t ws_size,
                              hipStream_t stream) {
    const float* ufea    = (const float*)d_in[0];
    const float* vfea    = (const float*)d_in[1];
    const int*   uv_rows = (const int*)d_in[2];
    const int*   uv_cols = (const int*)d_in[3];
    const float* uv_vals = (const float*)d_in[4];
    const int*   vu_rows = (const int*)d_in[5];
    const int*   vu_cols = (const int*)d_in[6];
    const float* vu_vals = (const float*)d_in[7];
    const float* user_W  = (const float*)d_in[8];
    const float* user_b  = (const float*)d_in[9];
    const float* item_W  = (const float*)d_in[10];
    const float* item_b  = (const float*)d_in[11];

    const int nnz = in_sizes[2];

    float* out_user = (float*)d_out;
    float* out_item = out_user + (size_t)N_USERS * DIM;

    const size_t UD = (size_t)N_USERS * DIM;
    const size_t ID = (size_t)N_ITEMS * DIM;

    char* p = (char*)d_ws;
    auto alloc = [&](size_t bytes) {
        char* q = p;
        p += (bytes + 255) & ~(size_t)255;
        return q;
    };
    _Float16* Uf = (_Float16*)alloc(UD * 2);
    _Float16* Vf = (_Float16*)alloc(ID * 2);
    _Float16* Ua = (_Float16*)alloc(UD * 2);
    _Float16* Ub = (_Float16*)alloc(UD * 2);
    _Float16* Va = (_Float16*)alloc(ID * 2);
    _Float16* Vb = (_Float16*)alloc(ID * 2);
    _Float16* Vc = (_Float16*)alloc(ID * 2);
    _Float16* Wt_user = (_Float16*)alloc((size_t)2 * 128 * 256 * 2);
    _Float16* Wt_item = (_Float16*)alloc((size_t)2 * 128 * 256 * 2);
    int*  uv_off = (int*)alloc((N_USERS + 1) * 4);
    int*  uv_cur = (int*)alloc((N_USERS + 1) * 4);
    int2* uv_edg = (int2*)alloc((size_t)nnz * 8);
    int*  vu_off = (int*)alloc((N_ITEMS + 1) * 4);
    int*  vu_cur = (int*)alloc((N_ITEMS + 1) * 4);
    int2* vu_edg = (int2*)alloc((size_t)nnz * 8);
    int*  bsums  = (int*)alloc(1024 * 4);
    unsigned long long* staged = (unsigned long long*)alloc((size_t)nnz * 8);
    int* bcur = (int*)alloc(4096 * 4);

    conv_f16_kernel<<<(int)((UD / 8 + 255) / 256), 256, 0, stream>>>(ufea, Uf, (int)(UD / 8));
    conv_f16_kernel<<<(int)((ID / 8 + 255) / 256), 256, 0, stream>>>(vfea, Vf, (int)(ID / 8));
    transposeW_kernel<<<256, 256, 0, stream>>>(user_W, Wt_user);
    transposeW_kernel<<<256, 256, 0, stream>>>(item_W, Wt_item);

    auto build_csr = [&](const int* rows, const int* cols, const float* vals,
                         int n_rows, int shift, int* off, int* cursor, int2* edges) {
        int eb = (nnz + 255) / 256;
        int nb1024 = (n_rows + 1023) / 1024;
        int nbuck  = (n_rows + (1 << shift) - 1) >> shift;
        hipMemsetAsync(cursor, 0, (size_t)(n_rows + 1) * 4, stream);
        hist_kernel<<<eb, 256, 0, stream>>>(rows, cursor, nnz);
        scan1_kernel<<<nb1024, 256, 0, stream>>>(cursor, off, bsums, n_rows);
        scan2_kernel<<<1, 256, 0, stream>>>(bsums, nb1024);
        scan3_kernel<<<nb1024, 256, 0, stream>>>(off, bsums, n_rows);
        binit_kernel<<<(nbuck + 255) / 256, 256, 0, stream>>>(off, bcur, n_rows, shift, nbuck);
        bucket_append_kernel<<<eb, 256, 0, stream>>>(rows, cols, vals, bcur,
                                                     staged, nnz, shift);
        hipMemcpyAsync(cursor, off, (size_t)n_rows * 4,
                       hipMemcpyDeviceToDevice, stream);
        bucket_scatter_kernel<<<nbuck, 256, 0, stream>>>(off, cursor, staged,
                                                         edges, n_rows, shift);
    };
    build_csr(uv_rows, uv_cols, uv_vals, N_USERS, 8, uv_off, uv_cur, uv_edg);
    build_csr(vu_rows, vu_cols, vu_vals, N_ITEMS, 7, vu_off, vu_cur, vu_edg);

    auto spmm_uv = [&](const _Float16* x, _Float16* out) {
        int blocks = (int)(((size_t)N_USERS * 16 + 255) / 256);
        spmm_csr_f16_kernel<<<blocks, 256, 0, stream>>>(uv_off, uv_edg, x, out, N_USERS);
    };
    auto spmm_vu = [&](const _Float16* x, _Float16* out) {
        int blocks = (int)(((size_t)N_ITEMS * 16 + 255) / 256);
        spmm_csr_f16_kernel<<<blocks, 256, 0, stream>>>(vu_off, vu_edg, x, out, N_ITEMS);
    };
    auto gemm_h = [&](const _Float16* ho, const _Float16* cur, const _Float16* Wt,
                      const float* bl, _Float16* out, int M) {
        gemm_f16_kernel<0><<<(M + 63) / 64, 256, 0, stream>>>(ho, cur, Wt, bl,
                                                              (float*)nullptr, out, M);
    };
    auto gemm_f = [&](const _Float16* ho, const _Float16* cur, const _Float16* Wt,
                      const float* bl, float* out, int M) {
        gemm_f16_kernel<1><<<(M + 63) / 64, 256, 0, stream>>>(ho, cur, Wt, bl,
                                                              out, (_Float16*)nullptr, M);
    };

    // ---------------- layer 0 (cur_u = Uf, cur_v = Vf) ----------------
    spmm_vu(Uf, Va);                  // TI  [I]
    spmm_uv(Vf, Ua);                  // TU  [U]
    spmm_vu(Ua, Vb);                  // HV  [I]  (TU consumed)
    spmm_uv(Va, Ub);                  // HU  [U]  (TI consumed)
    gemm_h(Ub, Uf, Wt_user, user_b, Ua, N_USERS);   // learn_user -> Ua
    gemm_h(Vb, Vf, Wt_item, item_b, Va, N_ITEMS);   // learn_item -> Va

    // ---------------- layer 1 (cur_u = Ua, cur_v = Va) -----------------
    spmm_vu(Ua, Vb);                  // TI'
    spmm_uv(Va, Ub);                  // TU'
    spmm_vu(Ub, Vc);                  // HV'  (TU' consumed)
    spmm_uv(Vb, Ub);                  // HU'  (overwrites TU', already consumed)
    gemm_f(Ub, Ua, Wt_user + 32768, user_b + DIM, out_user, N_USERS);
    gemm_f(Vc, Va, Wt_item + 32768, item_b + DIM, out_item, N_ITEMS);
}

// Round 5
// 1431.294 us; speedup vs baseline: 1.5667x; 1.5667x over previous
//
#include <hip/hip_runtime.h>

#define DIM 128
#define N_USERS 200000
#define N_ITEMS 100000

typedef __attribute__((ext_vector_type(8))) _Float16 half8;
typedef __attribute__((ext_vector_type(4))) _Float16 half4v;
typedef __attribute__((ext_vector_type(4))) float f32x4;

// ===========================================================================
// CSR build: histogram -> 3-phase exclusive scan -> windowed scatter
// ===========================================================================

__global__ __launch_bounds__(256) void hist_kernel(
    const int* __restrict__ rows, int* __restrict__ counts, int nnz)
{
    int e = blockIdx.x * blockDim.x + threadIdx.x;
    if (e < nnz) atomicAdd(&counts[rows[e]], 1);
}

__global__ __launch_bounds__(256) void scan1_kernel(
    const int* __restrict__ in, int* __restrict__ out,
    int* __restrict__ blockSums, int n)
{
    __shared__ int lds[256];
    int tid  = threadIdx.x;
    int base = blockIdx.x * 1024 + tid * 4;
    int v0 = (base + 0 < n) ? in[base + 0] : 0;
    int v1 = (base + 1 < n) ? in[base + 1] : 0;
    int v2 = (base + 2 < n) ? in[base + 2] : 0;
    int v3 = (base + 3 < n) ? in[base + 3] : 0;
    int s1 = v0 + v1, s2 = s1 + v2, s3 = s2 + v3;
    lds[tid] = s3;
    __syncthreads();
    for (int d = 1; d < 256; d <<= 1) {
        int t = 0;
        if (tid >= d) t = lds[tid - d];
        __syncthreads();
        lds[tid] += t;
        __syncthreads();
    }
    int excl = (tid > 0) ? lds[tid - 1] : 0;
    if (base + 0 < n) out[base + 1] = excl + v0;
    if (base + 1 < n) out[base + 2] = excl + s1;
    if (base + 2 < n) out[base + 3] = excl + s2;
    if (base + 3 < n) out[base + 4] = excl + s3;
    if (tid == 255) blockSums[blockIdx.x] = lds[255];
    if (blockIdx.x == 0 && tid == 0) out[0] = 0;
}

__global__ __launch_bounds__(256) void scan2_kernel(int* __restrict__ bs, int nb)
{
    __shared__ int lds[256];
    int tid  = threadIdx.x;
    int base = tid * 4;
    int v0 = (base + 0 < nb) ? bs[base + 0] : 0;
    int v1 = (base + 1 < nb) ? bs[base + 1] : 0;
    int v2 = (base + 2 < nb) ? bs[base + 2] : 0;
    int v3 = (base + 3 < nb) ? bs[base + 3] : 0;
    int s1 = v0 + v1, s2 = s1 + v2, s3 = s2 + v3;
    lds[tid] = s3;
    __syncthreads();
    for (int d = 1; d < 256; d <<= 1) {
        int t = 0;
        if (tid >= d) t = lds[tid - d];
        __syncthreads();
        lds[tid] += t;
        __syncthreads();
    }
    int run = (tid > 0) ? lds[tid - 1] : 0;
    if (base + 0 < nb) { int o = bs[base + 0]; bs[base + 0] = run; run += o; }
    if (base + 1 < nb) { int o = bs[base + 1]; bs[base + 1] = run; run += o; }
    if (base + 2 < nb) { int o = bs[base + 2]; bs[base + 2] = run; run += o; }
    if (base + 3 < nb) { int o = bs[base + 3]; bs[base + 3] = run; run += o; }
}

__global__ __launch_bounds__(256) void scan3_kernel(
    int* __restrict__ out, const int* __restrict__ bs, int n)
{
    int b = blockIdx.x;
    if (b == 0) return;
    int add  = bs[b];
    int base = b * 1024 + threadIdx.x * 4;
    if (base + 0 < n) out[base + 1] += add;
    if (base + 1 < n) out[base + 2] += add;
    if (base + 2 < n) out[base + 3] += add;
    if (base + 3 < n) out[base + 4] += add;
}

// Windowed scatter: only scatter edges whose row is in [rlo, rhi).
// Keeps the write window L2-resident (~4 MB) -> ~1x write amplification.
// Cursor array is per-row (200K/100K cursors) -> no atomic contention.
__global__ __launch_bounds__(256) void scatter_window_kernel(
    const int* __restrict__ rows, const int* __restrict__ cols,
    const float* __restrict__ vals, int* __restrict__ cursor,
    int2* __restrict__ edges, int nnz, int rlo, int rhi)
{
    int e = blockIdx.x * blockDim.x + threadIdx.x;
    if (e >= nnz) return;
    int r = rows[e];
    if (r < rlo || r >= rhi) return;
    int pos = atomicAdd(&cursor[r], 1);
    edges[pos] = make_int2(cols[e], __float_as_int(vals[e]));
}

// ===========================================================================
// fp32 -> fp16 table conversion (8 elems / thread)
// ===========================================================================
__global__ __launch_bounds__(256) void conv_f16_kernel(
    const float* __restrict__ src, _Float16* __restrict__ dst, int n8)
{
    int t = blockIdx.x * blockDim.x + threadIdx.x;
    if (t >= n8) return;
    const float4* s = reinterpret_cast<const float4*>(src) + (size_t)t * 2;
    float4 a = s[0], b = s[1];
    half8 h;
    h[0] = (_Float16)a.x; h[1] = (_Float16)a.y;
    h[2] = (_Float16)a.z; h[3] = (_Float16)a.w;
    h[4] = (_Float16)b.x; h[5] = (_Float16)b.y;
    h[6] = (_Float16)b.z; h[7] = (_Float16)b.w;
    reinterpret_cast<half8*>(dst)[t] = h;
}

// W [2][256][128] fp32  ->  Wt [2][128][256] fp16 (transposed per layer)
__global__ __launch_bounds__(256) void transposeW_kernel(
    const float* __restrict__ W, _Float16* __restrict__ Wt)
{
    int t = blockIdx.x * blockDim.x + threadIdx.x;   // 0..65535
    int l = t >> 15;
    int r = t & 32767;
    int k = r >> 7;
    int n = r & 127;
    Wt[(size_t)l * 32768 + n * 256 + k] = (_Float16)W[t];
}

// ===========================================================================
// CSR SpMM fp16: 16 lanes/row, 16B gathers, 2-way unrolled for gather MLP,
// fp32 accum, fp16 store
// ===========================================================================
__global__ __launch_bounds__(256) void spmm_csr_f16_kernel(
    const int* __restrict__ off, const int2* __restrict__ edges,
    const _Float16* __restrict__ x, _Float16* __restrict__ out, int n_rows)
{
    int t    = blockIdx.x * blockDim.x + threadIdx.x;
    int row  = t >> 4;
    int lane = t & 15;
    if (row >= n_rows) return;
    int beg = off[row], end = off[row + 1];
    float acc[8] = {0.f, 0.f, 0.f, 0.f, 0.f, 0.f, 0.f, 0.f};
    int k = beg;
    for (; k + 1 < end; k += 2) {
        int2 e0 = edges[k];
        int2 e1 = edges[k + 1];
        half8 x0 = *reinterpret_cast<const half8*>(x + (size_t)e0.x * DIM + lane * 8);
        half8 x1 = *reinterpret_cast<const half8*>(x + (size_t)e1.x * DIM + lane * 8);
        float v0 = __int_as_float(e0.y);
        float v1 = __int_as_float(e1.y);
#pragma unroll
        for (int i = 0; i < 8; ++i) acc[i] += v0 * (float)x0[i];
#pragma unroll
        for (int i = 0; i < 8; ++i) acc[i] += v1 * (float)x1[i];
    }
    if (k < end) {
        int2 e0 = edges[k];
        half8 x0 = *reinterpret_cast<const half8*>(x + (size_t)e0.x * DIM + lane * 8);
        float v0 = __int_as_float(e0.y);
#pragma unroll
        for (int i = 0; i < 8; ++i) acc[i] += v0 * (float)x0[i];
    }
    half8 o;
#pragma unroll
    for (int i = 0; i < 8; ++i) o[i] = (_Float16)acc[i];
    *reinterpret_cast<half8*>(out + (size_t)row * DIM + lane * 8) = o;
}

// ===========================================================================
// MFMA GEMM: out = relu( concat([HO, CUR]) @ W + b ), fp16 in, fp32 acc.
// Swapped operands: mfma(Wt_frag, A_frag) -> each lane holds 4 consecutive
// output features of one row -> vectorized stores. Block 256 = 4 waves.
// ===========================================================================
template<int OUT_F32>
__global__ __launch_bounds__(256) void gemm_f16_kernel(
    const _Float16* __restrict__ HO, const _Float16* __restrict__ CUR,
    const _Float16* __restrict__ Wt,   // [128][256] fp16
    const float* __restrict__ bias,    // [128] fp32
    float* __restrict__ outF, _Float16* __restrict__ outH, int M)
{
    int tid  = threadIdx.x;
    int wave = tid >> 6;
    int l    = tid & 63;
    int m    = l & 15;
    int kg   = l >> 4;
    int row  = blockIdx.x * 64 + wave * 16 + m;
    int rr   = min(row, M - 1);

    half8 afrag[8];
#pragma unroll
    for (int kk = 0; kk < 8; ++kk) {
        const _Float16* src = (kk < 4) ? HO : CUR;
        int k0 = (kk & 3) * 32 + kg * 8;
        afrag[kk] = *reinterpret_cast<const half8*>(src + (size_t)rr * DIM + k0);
    }

#pragma unroll
    for (int j = 0; j < 8; ++j) {
        f32x4 acc = {0.f, 0.f, 0.f, 0.f};
#pragma unroll
        for (int kk = 0; kk < 8; ++kk) {
            half8 wfrag = *reinterpret_cast<const half8*>(
                Wt + (size_t)(j * 16 + m) * 256 + kk * 32 + kg * 8);
            acc = __builtin_amdgcn_mfma_f32_16x16x32_f16(wfrag, afrag[kk], acc, 0, 0, 0);
        }
        int n0 = j * 16 + kg * 4;
        float4 bv = *reinterpret_cast<const float4*>(bias + n0);
        float o0 = fmaxf(acc[0] + bv.x, 0.f);
        float o1 = fmaxf(acc[1] + bv.y, 0.f);
        float o2 = fmaxf(acc[2] + bv.z, 0.f);
        float o3 = fmaxf(acc[3] + bv.w, 0.f);
        if (row < M) {
            if (OUT_F32) {
                float4 st = make_float4(o0, o1, o2, o3);
                *reinterpret_cast<float4*>(outF + (size_t)row * DIM + n0) = st;
            } else {
                half4v st;
                st[0] = (_Float16)o0; st[1] = (_Float16)o1;
                st[2] = (_Float16)o2; st[3] = (_Float16)o3;
                *reinterpret_cast<half4v*>(outH + (size_t)row * DIM + n0) = st;
            }
        }
    }
}

extern "C" void kernel_launch(void* const* d_in, const int* in_sizes, int n_in,
                              void* d_out, int out_size, void* d_ws, size_t ws_size,
                              hipStream_t stream) {
    const float* ufea    = (const float*)d_in[0];
    const float* vfea    = (const float*)d_in[1];
    const int*   uv_rows = (const int*)d_in[2];
    const int*   uv_cols = (const int*)d_in[3];
    const float* uv_vals = (const float*)d_in[4];
    const int*   vu_rows = (const int*)d_in[5];
    const int*   vu_cols = (const int*)d_in[6];
    const float* vu_vals = (const float*)d_in[7];
    const float* user_W  = (const float*)d_in[8];
    const float* user_b  = (const float*)d_in[9];
    const float* item_W  = (const float*)d_in[10];
    const float* item_b  = (const float*)d_in[11];

    const int nnz = in_sizes[2];

    float* out_user = (float*)d_out;
    float* out_item = out_user + (size_t)N_USERS * DIM;

    const size_t UD = (size_t)N_USERS * DIM;
    const size_t ID = (size_t)N_ITEMS * DIM;

    char* p = (char*)d_ws;
    auto alloc = [&](size_t bytes) {
        char* q = p;
        p += (bytes + 255) & ~(size_t)255;
        return q;
    };
    _Float16* Uf = (_Float16*)alloc(UD * 2);
    _Float16* Vf = (_Float16*)alloc(ID * 2);
    _Float16* Ua = (_Float16*)alloc(UD * 2);
    _Float16* Ub = (_Float16*)alloc(UD * 2);
    _Float16* Va = (_Float16*)alloc(ID * 2);
    _Float16* Vb = (_Float16*)alloc(ID * 2);
    _Float16* Vc = (_Float16*)alloc(ID * 2);
    _Float16* Wt_user = (_Float16*)alloc((size_t)2 * 128 * 256 * 2);
    _Float16* Wt_item = (_Float16*)alloc((size_t)2 * 128 * 256 * 2);
    int*  uv_off = (int*)alloc((N_USERS + 1) * 4);
    int*  uv_cur = (int*)alloc((N_USERS + 1) * 4);
    int2* uv_edg = (int2*)alloc((size_t)nnz * 8);
    int*  vu_off = (int*)alloc((N_ITEMS + 1) * 4);
    int*  vu_cur = (int*)alloc((N_ITEMS + 1) * 4);
    int2* vu_edg = (int2*)alloc((size_t)nnz * 8);
    int*  bsums  = (int*)alloc(1024 * 4);

    conv_f16_kernel<<<(int)((UD / 8 + 255) / 256), 256, 0, stream>>>(ufea, Uf, (int)(UD / 8));
    conv_f16_kernel<<<(int)((ID / 8 + 255) / 256), 256, 0, stream>>>(vfea, Vf, (int)(ID / 8));
    transposeW_kernel<<<256, 256, 0, stream>>>(user_W, Wt_user);
    transposeW_kernel<<<256, 256, 0, stream>>>(item_W, Wt_item);

    auto build_csr = [&](const int* rows, const int* cols, const float* vals,
                         int n_rows, int npass, int* off, int* cursor, int2* edges) {
        int eb = (nnz + 255) / 256;
        int nb1024 = (n_rows + 1023) / 1024;
        hipMemsetAsync(cursor, 0, (size_t)(n_rows + 1) * 4, stream);
        hist_kernel<<<eb, 256, 0, stream>>>(rows, cursor, nnz);
        scan1_kernel<<<nb1024, 256, 0, stream>>>(cursor, off, bsums, n_rows);
        scan2_kernel<<<1, 256, 0, stream>>>(bsums, nb1024);
        scan3_kernel<<<nb1024, 256, 0, stream>>>(off, bsums, n_rows);
        hipMemcpyAsync(cursor, off, (size_t)n_rows * 4,
                       hipMemcpyDeviceToDevice, stream);
        int wsize = (n_rows + npass - 1) / npass;
        for (int pass = 0; pass < npass; ++pass) {
            int rlo = pass * wsize;
            int rhi = min(rlo + wsize, n_rows);
            scatter_window_kernel<<<eb, 256, 0, stream>>>(rows, cols, vals, cursor,
                                                          edges, nnz, rlo, rhi);
        }
    };
    build_csr(uv_rows, uv_cols, uv_vals, N_USERS, 4, uv_off, uv_cur, uv_edg);
    build_csr(vu_rows, vu_cols, vu_vals, N_ITEMS, 4, vu_off, vu_cur, vu_edg);

    auto spmm_uv = [&](const _Float16* x, _Float16* out) {
        int blocks = (int)(((size_t)N_USERS * 16 + 255) / 256);
        spmm_csr_f16_kernel<<<blocks, 256, 0, stream>>>(uv_off, uv_edg, x, out, N_USERS);
    };
    auto spmm_vu = [&](const _Float16* x, _Float16* out) {
        int blocks = (int)(((size_t)N_ITEMS * 16 + 255) / 256);
        spmm_csr_f16_kernel<<<blocks, 256, 0, stream>>>(vu_off, vu_edg, x, out, N_ITEMS);
    };
    auto gemm_h = [&](const _Float16* ho, const _Float16* cur, const _Float16* Wt,
                      const float* bl, _Float16* out, int M) {
        gemm_f16_kernel<0><<<(M + 63) / 64, 256, 0, stream>>>(ho, cur, Wt, bl,
                                                              (float*)nullptr, out, M);
    };
    auto gemm_f = [&](const _Float16* ho, const _Float16* cur, const _Float16* Wt,
                      const float* bl, float* out, int M) {
        gemm_f16_kernel<1><<<(M + 63) / 64, 256, 0, stream>>>(ho, cur, Wt, bl,
                                                              out, (_Float16*)nullptr, M);
    };

    // ---------------- layer 0 (cur_u = Uf, cur_v = Vf) ----------------
    spmm_vu(Uf, Va);                  // TI  [I]
    spmm_uv(Vf, Ua);                  // TU  [U]
    spmm_vu(Ua, Vb);                  // HV  [I]  (TU consumed)
    spmm_uv(Va, Ub);                  // HU  [U]  (TI consumed)
    gemm_h(Ub, Uf, Wt_user, user_b, Ua, N_USERS);   // learn_user -> Ua
    gemm_h(Vb, Vf, Wt_item, item_b, Va, N_ITEMS);   // learn_item -> Va

    // ---------------- layer 1 (cur_u = Ua, cur_v = Va) -----------------
    spmm_vu(Ua, Vb);                  // TI'
    spmm_uv(Va, Ub);                  // TU'
    spmm_vu(Ub, Vc);                  // HV'  (TU' consumed)
    spmm_uv(Vb, Ub);                  // HU'  (overwrites TU', already consumed)
    gemm_f(Ub, Ua, Wt_user + 32768, user_b + DIM, out_user, N_USERS);
    gemm_f(Vc, Va, Wt_item + 32768, item_b + DIM, out_item, N_ITEMS);
}

// Round 6
// 1309.997 us; speedup vs baseline: 1.7118x; 1.0926x over previous
//
#include <hip/hip_runtime.h>

#define DIM 128
#define N_USERS 200000
#define N_ITEMS 100000

typedef __attribute__((ext_vector_type(8))) _Float16 half8;
typedef __attribute__((ext_vector_type(4))) _Float16 half4v;
typedef __attribute__((ext_vector_type(4))) float f32x4;

// ===========================================================================
// CSR build: histogram -> 3-phase exclusive scan -> windowed scatter
// ===========================================================================

__global__ __launch_bounds__(256) void hist_kernel(
    const int* __restrict__ rows, int* __restrict__ counts, int nnz)
{
    int e = blockIdx.x * blockDim.x + threadIdx.x;
    if (e < nnz) atomicAdd(&counts[rows[e]], 1);
}

__global__ __launch_bounds__(256) void scan1_kernel(
    const int* __restrict__ in, int* __restrict__ out,
    int* __restrict__ blockSums, int n)
{
    __shared__ int lds[256];
    int tid  = threadIdx.x;
    int base = blockIdx.x * 1024 + tid * 4;
    int v0 = (base + 0 < n) ? in[base + 0] : 0;
    int v1 = (base + 1 < n) ? in[base + 1] : 0;
    int v2 = (base + 2 < n) ? in[base + 2] : 0;
    int v3 = (base + 3 < n) ? in[base + 3] : 0;
    int s1 = v0 + v1, s2 = s1 + v2, s3 = s2 + v3;
    lds[tid] = s3;
    __syncthreads();
    for (int d = 1; d < 256; d <<= 1) {
        int t = 0;
        if (tid >= d) t = lds[tid - d];
        __syncthreads();
        lds[tid] += t;
        __syncthreads();
    }
    int excl = (tid > 0) ? lds[tid - 1] : 0;
    if (base + 0 < n) out[base + 1] = excl + v0;
    if (base + 1 < n) out[base + 2] = excl + s1;
    if (base + 2 < n) out[base + 3] = excl + s2;
    if (base + 3 < n) out[base + 4] = excl + s3;
    if (tid == 255) blockSums[blockIdx.x] = lds[255];
    if (blockIdx.x == 0 && tid == 0) out[0] = 0;
}

__global__ __launch_bounds__(256) void scan2_kernel(int* __restrict__ bs, int nb)
{
    __shared__ int lds[256];
    int tid  = threadIdx.x;
    int base = tid * 4;
    int v0 = (base + 0 < nb) ? bs[base + 0] : 0;
    int v1 = (base + 1 < nb) ? bs[base + 1] : 0;
    int v2 = (base + 2 < nb) ? bs[base + 2] : 0;
    int v3 = (base + 3 < nb) ? bs[base + 3] : 0;
    int s1 = v0 + v1, s2 = s1 + v2, s3 = s2 + v3;
    lds[tid] = s3;
    __syncthreads();
    for (int d = 1; d < 256; d <<= 1) {
        int t = 0;
        if (tid >= d) t = lds[tid - d];
        __syncthreads();
        lds[tid] += t;
        __syncthreads();
    }
    int run = (tid > 0) ? lds[tid - 1] : 0;
    if (base + 0 < nb) { int o = bs[base + 0]; bs[base + 0] = run; run += o; }
    if (base + 1 < nb) { int o = bs[base + 1]; bs[base + 1] = run; run += o; }
    if (base + 2 < nb) { int o = bs[base + 2]; bs[base + 2] = run; run += o; }
    if (base + 3 < nb) { int o = bs[base + 3]; bs[base + 3] = run; run += o; }
}

__global__ __launch_bounds__(256) void scan3_kernel(
    int* __restrict__ out, const int* __restrict__ bs, int n)
{
    int b = blockIdx.x;
    if (b == 0) return;
    int add  = bs[b];
    int base = b * 1024 + threadIdx.x * 4;
    if (base + 0 < n) out[base + 1] += add;
    if (base + 1 < n) out[base + 2] += add;
    if (base + 2 < n) out[base + 3] += add;
    if (base + 3 < n) out[base + 4] += add;
}

// Windowed scatter: only edges whose row is in [rlo, rhi) -> write window
// stays L2-resident; per-row cursors -> no atomic contention.
__global__ __launch_bounds__(256) void scatter_window_kernel(
    const int* __restrict__ rows, const int* __restrict__ cols,
    const float* __restrict__ vals, int* __restrict__ cursor,
    int2* __restrict__ edges, int nnz, int rlo, int rhi)
{
    int e = blockIdx.x * blockDim.x + threadIdx.x;
    if (e >= nnz) return;
    int r = rows[e];
    if (r < rlo || r >= rhi) return;
    int pos = atomicAdd(&cursor[r], 1);
    edges[pos] = make_int2(cols[e], __float_as_int(vals[e]));
}

// ===========================================================================
// fp32 -> fp16 table conversion (8 elems / thread)
// ===========================================================================
__global__ __launch_bounds__(256) void conv_f16_kernel(
    const float* __restrict__ src, _Float16* __restrict__ dst, int n8)
{
    int t = blockIdx.x * blockDim.x + threadIdx.x;
    if (t >= n8) return;
    const float4* s = reinterpret_cast<const float4*>(src) + (size_t)t * 2;
    float4 a = s[0], b = s[1];
    half8 h;
    h[0] = (_Float16)a.x; h[1] = (_Float16)a.y;
    h[2] = (_Float16)a.z; h[3] = (_Float16)a.w;
    h[4] = (_Float16)b.x; h[5] = (_Float16)b.y;
    h[6] = (_Float16)b.z; h[7] = (_Float16)b.w;
    reinterpret_cast<half8*>(dst)[t] = h;
}

// W [2][256][128] fp32  ->  Wt [2][128][256] fp16 (transposed per layer)
__global__ __launch_bounds__(256) void transposeW_kernel(
    const float* __restrict__ W, _Float16* __restrict__ Wt)
{
    int t = blockIdx.x * blockDim.x + threadIdx.x;   // 0..65535
    int l = t >> 15;
    int r = t & 32767;
    int k = r >> 7;
    int n = r & 127;
    Wt[(size_t)l * 32768 + n * 256 + k] = (_Float16)W[t];
}

// ===========================================================================
// CSR SpMM fp16: 16 lanes/row, 16B gathers, 2-way unrolled,
// fp32 accum, fp16 store
// ===========================================================================
__global__ __launch_bounds__(256) void spmm_csr_f16_kernel(
    const int* __restrict__ off, const int2* __restrict__ edges,
    const _Float16* __restrict__ x, _Float16* __restrict__ out, int n_rows)
{
    int t    = blockIdx.x * blockDim.x + threadIdx.x;
    int row  = t >> 4;
    int lane = t & 15;
    if (row >= n_rows) return;
    int beg = off[row], end = off[row + 1];
    float acc[8] = {0.f, 0.f, 0.f, 0.f, 0.f, 0.f, 0.f, 0.f};
    int k = beg;
    for (; k + 1 < end; k += 2) {
        int2 e0 = edges[k];
        int2 e1 = edges[k + 1];
        half8 x0 = *reinterpret_cast<const half8*>(x + (size_t)e0.x * DIM + lane * 8);
        half8 x1 = *reinterpret_cast<const half8*>(x + (size_t)e1.x * DIM + lane * 8);
        float v0 = __int_as_float(e0.y);
        float v1 = __int_as_float(e1.y);
#pragma unroll
        for (int i = 0; i < 8; ++i) acc[i] += v0 * (float)x0[i];
#pragma unroll
        for (int i = 0; i < 8; ++i) acc[i] += v1 * (float)x1[i];
    }
    if (k < end) {
        int2 e0 = edges[k];
        half8 x0 = *reinterpret_cast<const half8*>(x + (size_t)e0.x * DIM + lane * 8);
        float v0 = __int_as_float(e0.y);
#pragma unroll
        for (int i = 0; i < 8; ++i) acc[i] += v0 * (float)x0[i];
    }
    half8 o;
#pragma unroll
    for (int i = 0; i < 8; ++i) o[i] = (_Float16)acc[i];
    *reinterpret_cast<half8*>(out + (size_t)row * DIM + lane * 8) = o;
}

// ===========================================================================
// MFMA GEMM, W-in-registers: out = relu( concat([HO,CUR]) @ W + b ).
// 4 waves/block; wave w owns output features [w*32, w*32+32) (j = 2w, 2w+1).
// W fragments (64 VGPR) + bias hoisted out of the row loop -> per 16-row
// tile only 8 A-fragment loads (streaming) + 16 MFMAs. Block = 128 rows.
// ===========================================================================
template<int OUT_F32>
__global__ __launch_bounds__(256) void gemm_f16_kernel(
    const _Float16* __restrict__ HO, const _Float16* __restrict__ CUR,
    const _Float16* __restrict__ Wt,   // [128][256] fp16
    const float* __restrict__ bias,    // [128] fp32
    float* __restrict__ outF, _Float16* __restrict__ outH, int M)
{
    const int TILES = 8;
    int tid  = threadIdx.x;
    int wave = tid >> 6;
    int l    = tid & 63;
    int m    = l & 15;       // A-row within tile (= D col)
    int kg   = l >> 4;       // 0..3 k-group (D rows kg*4..kg*4+3)

    // Hoisted, loop-invariant W fragments and bias for j = wave*2 + jj
    half8 wfrag[2][8];
    float4 bv[2];
#pragma unroll
    for (int jj = 0; jj < 2; ++jj) {
        int j = wave * 2 + jj;
#pragma unroll
        for (int kk = 0; kk < 8; ++kk)
            wfrag[jj][kk] = *reinterpret_cast<const half8*>(
                Wt + (size_t)(j * 16 + m) * 256 + kk * 32 + kg * 8);
        bv[jj] = *reinterpret_cast<const float4*>(bias + j * 16 + kg * 4);
    }

    int base = blockIdx.x * (TILES * 16);
#pragma unroll 2
    for (int t = 0; t < TILES; ++t) {
        int row = base + t * 16 + m;
        int rr  = min(row, M - 1);
        half8 afrag[8];
#pragma unroll
        for (int kk = 0; kk < 8; ++kk) {
            const _Float16* src = (kk < 4) ? HO : CUR;
            int k0 = (kk & 3) * 32 + kg * 8;
            afrag[kk] = *reinterpret_cast<const half8*>(src + (size_t)rr * DIM + k0);
        }
#pragma unroll
        for (int jj = 0; jj < 2; ++jj) {
            f32x4 acc = {0.f, 0.f, 0.f, 0.f};
#pragma unroll
            for (int kk = 0; kk < 8; ++kk)
                acc = __builtin_amdgcn_mfma_f32_16x16x32_f16(
                    wfrag[jj][kk], afrag[kk], acc, 0, 0, 0);
            int n0 = (wave * 2 + jj) * 16 + kg * 4;
            float o0 = fmaxf(acc[0] + bv[jj].x, 0.f);
            float o1 = fmaxf(acc[1] + bv[jj].y, 0.f);
            float o2 = fmaxf(acc[2] + bv[jj].z, 0.f);
            float o3 = fmaxf(acc[3] + bv[jj].w, 0.f);
            if (row < M) {
                if (OUT_F32) {
                    float4 st = make_float4(o0, o1, o2, o3);
                    *reinterpret_cast<float4*>(outF + (size_t)row * DIM + n0) = st;
                } else {
                    half4v st;
                    st[0] = (_Float16)o0; st[1] = (_Float16)o1;
                    st[2] = (_Float16)o2; st[3] = (_Float16)o3;
                    *reinterpret_cast<half4v*>(outH + (size_t)row * DIM + n0) = st;
                }
            }
        }
    }
}

extern "C" void kernel_launch(void* const* d_in, const int* in_sizes, int n_in,
                              void* d_out, int out_size, void* d_ws, size_t ws_size,
                              hipStream_t stream) {
    const float* ufea    = (const float*)d_in[0];
    const float* vfea    = (const float*)d_in[1];
    const int*   uv_rows = (const int*)d_in[2];
    const int*   uv_cols = (const int*)d_in[3];
    const float* uv_vals = (const float*)d_in[4];
    const int*   vu_rows = (const int*)d_in[5];
    const int*   vu_cols = (const int*)d_in[6];
    const float* vu_vals = (const float*)d_in[7];
    const float* user_W  = (const float*)d_in[8];
    const float* user_b  = (const float*)d_in[9];
    const float* item_W  = (const float*)d_in[10];
    const float* item_b  = (const float*)d_in[11];

    const int nnz = in_sizes[2];

    float* out_user = (float*)d_out;
    float* out_item = out_user + (size_t)N_USERS * DIM;

    const size_t UD = (size_t)N_USERS * DIM;
    const size_t ID = (size_t)N_ITEMS * DIM;

    char* p = (char*)d_ws;
    auto alloc = [&](size_t bytes) {
        char* q = p;
        p += (bytes + 255) & ~(size_t)255;
        return q;
    };
    _Float16* Uf = (_Float16*)alloc(UD * 2);
    _Float16* Vf = (_Float16*)alloc(ID * 2);
    _Float16* Ua = (_Float16*)alloc(UD * 2);
    _Float16* Ub = (_Float16*)alloc(UD * 2);
    _Float16* Va = (_Float16*)alloc(ID * 2);
    _Float16* Vb = (_Float16*)alloc(ID * 2);
    _Float16* Vc = (_Float16*)alloc(ID * 2);
    _Float16* Wt_user = (_Float16*)alloc((size_t)2 * 128 * 256 * 2);
    _Float16* Wt_item = (_Float16*)alloc((size_t)2 * 128 * 256 * 2);
    int*  uv_off = (int*)alloc((N_USERS + 1) * 4);
    int*  uv_cur = (int*)alloc((N_USERS + 1) * 4);
    int2* uv_edg = (int2*)alloc((size_t)nnz * 8);
    int*  vu_off = (int*)alloc((N_ITEMS + 1) * 4);
    int*  vu_cur = (int*)alloc((N_ITEMS + 1) * 4);
    int2* vu_edg = (int2*)alloc((size_t)nnz * 8);
    int*  bsums  = (int*)alloc(1024 * 4);

    conv_f16_kernel<<<(int)((UD / 8 + 255) / 256), 256, 0, stream>>>(ufea, Uf, (int)(UD / 8));
    conv_f16_kernel<<<(int)((ID / 8 + 255) / 256), 256, 0, stream>>>(vfea, Vf, (int)(ID / 8));
    transposeW_kernel<<<256, 256, 0, stream>>>(user_W, Wt_user);
    transposeW_kernel<<<256, 256, 0, stream>>>(item_W, Wt_item);

    auto build_csr = [&](const int* rows, const int* cols, const float* vals,
                         int n_rows, int npass, int* off, int* cursor, int2* edges) {
        int eb = (nnz + 255) / 256;
        int nb1024 = (n_rows + 1023) / 1024;
        hipMemsetAsync(cursor, 0, (size_t)(n_rows + 1) * 4, stream);
        hist_kernel<<<eb, 256, 0, stream>>>(rows, cursor, nnz);
        scan1_kernel<<<nb1024, 256, 0, stream>>>(cursor, off, bsums, n_rows);
        scan2_kernel<<<1, 256, 0, stream>>>(bsums, nb1024);
        scan3_kernel<<<nb1024, 256, 0, stream>>>(off, bsums, n_rows);
        hipMemcpyAsync(cursor, off, (size_t)n_rows * 4,
                       hipMemcpyDeviceToDevice, stream);
        int wsize = (n_rows + npass - 1) / npass;
        for (int pass = 0; pass < npass; ++pass) {
            int rlo = pass * wsize;
            int rhi = min(rlo + wsize, n_rows);
            scatter_window_kernel<<<eb, 256, 0, stream>>>(rows, cols, vals, cursor,
                                                          edges, nnz, rlo, rhi);
        }
    };
    build_csr(uv_rows, uv_cols, uv_vals, N_USERS, 4, uv_off, uv_cur, uv_edg);
    build_csr(vu_rows, vu_cols, vu_vals, N_ITEMS, 4, vu_off, vu_cur, vu_edg);

    auto spmm_uv = [&](const _Float16* x, _Float16* out) {
        int blocks = (int)(((size_t)N_USERS * 16 + 255) / 256);
        spmm_csr_f16_kernel<<<blocks, 256, 0, stream>>>(uv_off, uv_edg, x, out, N_USERS);
    };
    auto spmm_vu = [&](const _Float16* x, _Float16* out) {
        int blocks = (int)(((size_t)N_ITEMS * 16 + 255) / 256);
        spmm_csr_f16_kernel<<<blocks, 256, 0, stream>>>(vu_off, vu_edg, x, out, N_ITEMS);
    };
    auto gemm_h = [&](const _Float16* ho, const _Float16* cur, const _Float16* Wt,
                      const float* bl, _Float16* out, int M) {
        gemm_f16_kernel<0><<<(M + 127) / 128, 256, 0, stream>>>(ho, cur, Wt, bl,
                                                                (float*)nullptr, out, M);
    };
    auto gemm_f = [&](const _Float16* ho, const _Float16* cur, const _Float16* Wt,
                      const float* bl, float* out, int M) {
        gemm_f16_kernel<1><<<(M + 127) / 128, 256, 0, stream>>>(ho, cur, Wt, bl,
                                                                out, (_Float16*)nullptr, M);
    };

    // ---------------- layer 0 (cur_u = Uf, cur_v = Vf) ----------------
    spmm_vu(Uf, Va);                  // TI  [I]
    spmm_uv(Vf, Ua);                  // TU  [U]
    spmm_vu(Ua, Vb);                  // HV  [I]  (TU consumed)
    spmm_uv(Va, Ub);                  // HU  [U]  (TI consumed)
    gemm_h(Ub, Uf, Wt_user, user_b, Ua, N_USERS);   // learn_user -> Ua
    gemm_h(Vb, Vf, Wt_item, item_b, Va, N_ITEMS);   // learn_item -> Va

    // ---------------- layer 1 (cur_u = Ua, cur_v = Va) -----------------
    spmm_vu(Ua, Vb);                  // TI'
    spmm_uv(Va, Ub);                  // TU'
    spmm_vu(Ub, Vc);                  // HV'  (TU' consumed)
    spmm_uv(Vb, Ub);                  // HU'  (overwrites TU', already consumed)
    gemm_f(Ub, Ua, Wt_user + 32768, user_b + DIM, out_user, N_USERS);
    gemm_f(Vc, Va, Wt_item + 32768, item_b + DIM, out_item, N_ITEMS);
}

// Round 8
// 1234.672 us; speedup vs baseline: 1.8162x; 1.0610x over previous
//
#include <hip/hip_runtime.h>

#define DIM 128
#define N_USERS 200000
#define N_ITEMS 100000

typedef __attribute__((ext_vector_type(8))) _Float16 half8;
typedef __attribute__((ext_vector_type(4))) _Float16 half4v;
typedef __attribute__((ext_vector_type(4))) float f32x4;

// ===========================================================================
// CSR build: histogram -> 3-phase exclusive scan -> windowed scatter
// ===========================================================================

__global__ __launch_bounds__(256) void hist_kernel(
    const int* __restrict__ rows, int* __restrict__ counts, int nnz)
{
    int e = blockIdx.x * blockDim.x + threadIdx.x;
    if (e < nnz) atomicAdd(&counts[rows[e]], 1);
}

__global__ __launch_bounds__(256) void scan1_kernel(
    const int* __restrict__ in, int* __restrict__ out,
    int* __restrict__ blockSums, int n)
{
    __shared__ int lds[256];
    int tid  = threadIdx.x;
    int base = blockIdx.x * 1024 + tid * 4;
    int v0 = (base + 0 < n) ? in[base + 0] : 0;
    int v1 = (base + 1 < n) ? in[base + 1] : 0;
    int v2 = (base + 2 < n) ? in[base + 2] : 0;
    int v3 = (base + 3 < n) ? in[base + 3] : 0;
    int s1 = v0 + v1, s2 = s1 + v2, s3 = s2 + v3;
    lds[tid] = s3;
    __syncthreads();
    for (int d = 1; d < 256; d <<= 1) {
        int t = 0;
        if (tid >= d) t = lds[tid - d];
        __syncthreads();
        lds[tid] += t;
        __syncthreads();
    }
    int excl = (tid > 0) ? lds[tid - 1] : 0;
    if (base + 0 < n) out[base + 1] = excl + v0;
    if (base + 1 < n) out[base + 2] = excl + s1;
    if (base + 2 < n) out[base + 3] = excl + s2;
    if (base + 3 < n) out[base + 4] = excl + s3;
    if (tid == 255) blockSums[blockIdx.x] = lds[255];
    if (blockIdx.x == 0 && tid == 0) out[0] = 0;
}

__global__ __launch_bounds__(256) void scan2_kernel(int* __restrict__ bs, int nb)
{
    __shared__ int lds[256];
    int tid  = threadIdx.x;
    int base = tid * 4;
    int v0 = (base + 0 < nb) ? bs[base + 0] : 0;
    int v1 = (base + 1 < nb) ? bs[base + 1] : 0;
    int v2 = (base + 2 < nb) ? bs[base + 2] : 0;
    int v3 = (base + 3 < nb) ? bs[base + 3] : 0;
    int s1 = v0 + v1, s2 = s1 + v2, s3 = s2 + v3;
    lds[tid] = s3;
    __syncthreads();
    for (int d = 1; d < 256; d <<= 1) {
        int t = 0;
        if (tid >= d) t = lds[tid - d];
        __syncthreads();
        lds[tid] += t;
        __syncthreads();
    }
    int run = (tid > 0) ? lds[tid - 1] : 0;
    if (base + 0 < nb) { int o = bs[base + 0]; bs[base + 0] = run; run += o; }
    if (base + 1 < nb) { int o = bs[base + 1]; bs[base + 1] = run; run += o; }
    if (base + 2 < nb) { int o = bs[base + 2]; bs[base + 2] = run; run += o; }
    if (base + 3 < nb) { int o = bs[base + 3]; bs[base + 3] = run; run += o; }
}

__global__ __launch_bounds__(256) void scan3_kernel(
    int* __restrict__ out, const int* __restrict__ bs, int n)
{
    int b = blockIdx.x;
    if (b == 0) return;
    int add  = bs[b];
    int base = b * 1024 + threadIdx.x * 4;
    if (base + 0 < n) out[base + 1] += add;
    if (base + 1 < n) out[base + 2] += add;
    if (base + 2 < n) out[base + 3] += add;
    if (base + 3 < n) out[base + 4] += add;
}

// Windowed scatter: only edges whose row is in [rlo, rhi) -> write window
// stays L2-resident; per-row cursors -> no atomic contention.
__global__ __launch_bounds__(256) void scatter_window_kernel(
    const int* __restrict__ rows, const int* __restrict__ cols,
    const float* __restrict__ vals, int* __restrict__ cursor,
    int2* __restrict__ edges, int nnz, int rlo, int rhi)
{
    int e = blockIdx.x * blockDim.x + threadIdx.x;
    if (e >= nnz) return;
    int r = rows[e];
    if (r < rlo || r >= rhi) return;
    int pos = atomicAdd(&cursor[r], 1);
    edges[pos] = make_int2(cols[e], __float_as_int(vals[e]));
}

// ===========================================================================
// fp32 -> fp16 table conversion (8 elems / thread)
// ===========================================================================
__global__ __launch_bounds__(256) void conv_f16_kernel(
    const float* __restrict__ src, _Float16* __restrict__ dst, int n8)
{
    int t = blockIdx.x * blockDim.x + threadIdx.x;
    if (t >= n8) return;
    const float4* s = reinterpret_cast<const float4*>(src) + (size_t)t * 2;
    float4 a = s[0], b = s[1];
    half8 h;
    h[0] = (_Float16)a.x; h[1] = (_Float16)a.y;
    h[2] = (_Float16)a.z; h[3] = (_Float16)a.w;
    h[4] = (_Float16)b.x; h[5] = (_Float16)b.y;
    h[6] = (_Float16)b.z; h[7] = (_Float16)b.w;
    reinterpret_cast<half8*>(dst)[t] = h;
}

// W [2][256][128] fp32  ->  Wt [2][128][256] fp16 (transposed per layer)
__global__ __launch_bounds__(256) void transposeW_kernel(
    const float* __restrict__ W, _Float16* __restrict__ Wt)
{
    int t = blockIdx.x * blockDim.x + threadIdx.x;   // 0..65535
    int l = t >> 15;
    int r = t & 32767;
    int k = r >> 7;
    int n = r & 127;
    Wt[(size_t)l * 32768 + n * 256 + k] = (_Float16)W[t];
}

// ===========================================================================
// Dual CSR SpMM fp16: two independent SpMMs (graph A rows first, then B) in
// one launch. 16 lanes/row, 16B gathers, 4-way unrolled for gather MLP,
// fp32 accum, fp16 store.
// NOTE: callers must guarantee outA/outB do not alias xA/xB of the SAME
// launch (blocks run concurrently).
// ===========================================================================
__global__ __launch_bounds__(256) void spmm_dual_kernel(
    const int* __restrict__ offA, const int2* __restrict__ edgA,
    const _Float16* __restrict__ xA, _Float16* __restrict__ outA, int nA,
    const int* __restrict__ offB, const int2* __restrict__ edgB,
    const _Float16* __restrict__ xB, _Float16* __restrict__ outB, int nB)
{
    int t    = blockIdx.x * blockDim.x + threadIdx.x;
    int grp  = t >> 4;
    int lane = t & 15;

    const int*      off;
    const int2*     edg;
    const _Float16* x;
    _Float16*       out;
    int row;
    if (grp < nA) {
        off = offA; edg = edgA; x = xA; out = outA; row = grp;
    } else {
        row = grp - nA;
        if (row >= nB) return;
        off = offB; edg = edgB; x = xB; out = outB;
    }

    int beg = off[row], end = off[row + 1];
    float acc[8] = {0.f, 0.f, 0.f, 0.f, 0.f, 0.f, 0.f, 0.f};
    int k = beg;
    for (; k + 3 < end; k += 4) {
        int2 e0 = edg[k];
        int2 e1 = edg[k + 1];
        int2 e2 = edg[k + 2];
        int2 e3 = edg[k + 3];
        half8 x0 = *reinterpret_cast<const half8*>(x + (size_t)e0.x * DIM + lane * 8);
        half8 x1 = *reinterpret_cast<const half8*>(x + (size_t)e1.x * DIM + lane * 8);
        half8 x2 = *reinterpret_cast<const half8*>(x + (size_t)e2.x * DIM + lane * 8);
        half8 x3 = *reinterpret_cast<const half8*>(x + (size_t)e3.x * DIM + lane * 8);
        float v0 = __int_as_float(e0.y);
        float v1 = __int_as_float(e1.y);
        float v2 = __int_as_float(e2.y);
        float v3 = __int_as_float(e3.y);
#pragma unroll
        for (int i = 0; i < 8; ++i) acc[i] += v0 * (float)x0[i];
#pragma unroll
        for (int i = 0; i < 8; ++i) acc[i] += v1 * (float)x1[i];
#pragma unroll
        for (int i = 0; i < 8; ++i) acc[i] += v2 * (float)x2[i];
#pragma unroll
        for (int i = 0; i < 8; ++i) acc[i] += v3 * (float)x3[i];
    }
    for (; k < end; ++k) {
        int2 e0 = edg[k];
        half8 x0 = *reinterpret_cast<const half8*>(x + (size_t)e0.x * DIM + lane * 8);
        float v0 = __int_as_float(e0.y);
#pragma unroll
        for (int i = 0; i < 8; ++i) acc[i] += v0 * (float)x0[i];
    }
    half8 o;
#pragma unroll
    for (int i = 0; i < 8; ++i) o[i] = (_Float16)acc[i];
    *reinterpret_cast<half8*>(out + (size_t)row * DIM + lane * 8) = o;
}

// ===========================================================================
// Dual MFMA GEMM, W-in-registers: user blocks [0, ublocks), item blocks rest.
// Per block: 4 waves, wave w owns output features [w*32, w*32+32).
// W frags (64 VGPR) + bias hoisted; per 16-row tile only 8 A loads + 16 MFMA.
// Block covers 128 rows.
// ===========================================================================
template<int OUT_F32>
__global__ __launch_bounds__(256) void gemm_dual_kernel(
    const _Float16* __restrict__ HOu, const _Float16* __restrict__ CURu,
    const _Float16* __restrict__ Wtu, const float* __restrict__ bu,
    float* __restrict__ outFu, _Float16* __restrict__ outHu, int Mu, int ublocks,
    const _Float16* __restrict__ HOi, const _Float16* __restrict__ CURi,
    const _Float16* __restrict__ Wti, const float* __restrict__ bi,
    float* __restrict__ outFi, _Float16* __restrict__ outHi, int Mi)
{
    const int TILES = 8;
    int bid = blockIdx.x;
    const _Float16 *HO, *CUR, *Wt;
    const float* bias;
    float* outF;
    _Float16* outH;
    int M;
    if (bid < ublocks) {
        HO = HOu; CUR = CURu; Wt = Wtu; bias = bu; outF = outFu; outH = outHu; M = Mu;
    } else {
        bid -= ublocks;
        HO = HOi; CUR = CURi; Wt = Wti; bias = bi; outF = outFi; outH = outHi; M = Mi;
    }

    int tid  = threadIdx.x;
    int wave = tid >> 6;
    int l    = tid & 63;
    int m    = l & 15;       // A-row within tile (= D col)
    int kg   = l >> 4;       // 0..3 k-group (D rows kg*4..kg*4+3)

    half8 wfrag[2][8];
    float4 bv[2];
#pragma unroll
    for (int jj = 0; jj < 2; ++jj) {
        int j = wave * 2 + jj;
#pragma unroll
        for (int kk = 0; kk < 8; ++kk)
            wfrag[jj][kk] = *reinterpret_cast<const half8*>(
                Wt + (size_t)(j * 16 + m) * 256 + kk * 32 + kg * 8);
        bv[jj] = *reinterpret_cast<const float4*>(bias + j * 16 + kg * 4);
    }

    int base = bid * (TILES * 16);
#pragma unroll 2
    for (int t = 0; t < TILES; ++t) {
        int row = base + t * 16 + m;
        int rr  = min(row, M - 1);
        half8 afrag[8];
#pragma unroll
        for (int kk = 0; kk < 8; ++kk) {
            const _Float16* src = (kk < 4) ? HO : CUR;
            int k0 = (kk & 3) * 32 + kg * 8;
            afrag[kk] = *reinterpret_cast<const half8*>(src + (size_t)rr * DIM + k0);
        }
#pragma unroll
        for (int jj = 0; jj < 2; ++jj) {
            f32x4 acc = {0.f, 0.f, 0.f, 0.f};
#pragma unroll
            for (int kk = 0; kk < 8; ++kk)
                acc = __builtin_amdgcn_mfma_f32_16x16x32_f16(
                    wfrag[jj][kk], afrag[kk], acc, 0, 0, 0);
            int n0 = (wave * 2 + jj) * 16 + kg * 4;
            float o0 = fmaxf(acc[0] + bv[jj].x, 0.f);
            float o1 = fmaxf(acc[1] + bv[jj].y, 0.f);
            float o2 = fmaxf(acc[2] + bv[jj].z, 0.f);
            float o3 = fmaxf(acc[3] + bv[jj].w, 0.f);
            if (row < M) {
                if (OUT_F32) {
                    float4 st = make_float4(o0, o1, o2, o3);
                    *reinterpret_cast<float4*>(outF + (size_t)row * DIM + n0) = st;
                } else {
                    half4v st;
                    st[0] = (_Float16)o0; st[1] = (_Float16)o1;
                    st[2] = (_Float16)o2; st[3] = (_Float16)o3;
                    *reinterpret_cast<half4v*>(outH + (size_t)row * DIM + n0) = st;
                }
            }
        }
    }
}

extern "C" void kernel_launch(void* const* d_in, const int* in_sizes, int n_in,
                              void* d_out, int out_size, void* d_ws, size_t ws_size,
                              hipStream_t stream) {
    const float* ufea    = (const float*)d_in[0];
    const float* vfea    = (const float*)d_in[1];
    const int*   uv_rows = (const int*)d_in[2];
    const int*   uv_cols = (const int*)d_in[3];
    const float* uv_vals = (const float*)d_in[4];
    const int*   vu_rows = (const int*)d_in[5];
    const int*   vu_cols = (const int*)d_in[6];
    const float* vu_vals = (const float*)d_in[7];
    const float* user_W  = (const float*)d_in[8];
    const float* user_b  = (const float*)d_in[9];
    const float* item_W  = (const float*)d_in[10];
    const float* item_b  = (const float*)d_in[11];

    const int nnz = in_sizes[2];

    float* out_user = (float*)d_out;
    float* out_item = out_user + (size_t)N_USERS * DIM;

    const size_t UD = (size_t)N_USERS * DIM;
    const size_t ID = (size_t)N_ITEMS * DIM;

    char* p = (char*)d_ws;
    auto alloc = [&](size_t bytes) {
        char* q = p;
        p += (bytes + 255) & ~(size_t)255;
        return q;
    };
    _Float16* Uf = (_Float16*)alloc(UD * 2);
    _Float16* Vf = (_Float16*)alloc(ID * 2);
    _Float16* Ua = (_Float16*)alloc(UD * 2);
    _Float16* Ub = (_Float16*)alloc(UD * 2);
    _Float16* Uc = (_Float16*)alloc(UD * 2);   // breaks layer-1 WAR alias
    _Float16* Va = (_Float16*)alloc(ID * 2);
    _Float16* Vb = (_Float16*)alloc(ID * 2);
    _Float16* Vc = (_Float16*)alloc(ID * 2);
    _Float16* Wt_user = (_Float16*)alloc((size_t)2 * 128 * 256 * 2);
    _Float16* Wt_item = (_Float16*)alloc((size_t)2 * 128 * 256 * 2);
    int*  uv_off = (int*)alloc((N_USERS + 1) * 4);
    int*  uv_cur = (int*)alloc((N_USERS + 1) * 4);
    int2* uv_edg = (int2*)alloc((size_t)nnz * 8);
    int*  vu_off = (int*)alloc((N_ITEMS + 1) * 4);
    int*  vu_cur = (int*)alloc((N_ITEMS + 1) * 4);
    int2* vu_edg = (int2*)alloc((size_t)nnz * 8);
    int*  bsums  = (int*)alloc(1024 * 4);

    conv_f16_kernel<<<(int)((UD / 8 + 255) / 256), 256, 0, stream>>>(ufea, Uf, (int)(UD / 8));
    conv_f16_kernel<<<(int)((ID / 8 + 255) / 256), 256, 0, stream>>>(vfea, Vf, (int)(ID / 8));
    transposeW_kernel<<<256, 256, 0, stream>>>(user_W, Wt_user);
    transposeW_kernel<<<256, 256, 0, stream>>>(item_W, Wt_item);

    auto build_csr = [&](const int* rows, const int* cols, const float* vals,
                         int n_rows, int npass, int* off, int* cursor, int2* edges) {
        int eb = (nnz + 255) / 256;
        int nb1024 = (n_rows + 1023) / 1024;
        hipMemsetAsync(cursor, 0, (size_t)(n_rows + 1) * 4, stream);
        hist_kernel<<<eb, 256, 0, stream>>>(rows, cursor, nnz);
        scan1_kernel<<<nb1024, 256, 0, stream>>>(cursor, off, bsums, n_rows);
        scan2_kernel<<<1, 256, 0, stream>>>(bsums, nb1024);
        scan3_kernel<<<nb1024, 256, 0, stream>>>(off, bsums, n_rows);
        hipMemcpyAsync(cursor, off, (size_t)n_rows * 4,
                       hipMemcpyDeviceToDevice, stream);
        int wsize = (n_rows + npass - 1) / npass;
        for (int pass = 0; pass < npass; ++pass) {
            int rlo = pass * wsize;
            int rhi = min(rlo + wsize, n_rows);
            scatter_window_kernel<<<eb, 256, 0, stream>>>(rows, cols, vals, cursor,
                                                          edges, nnz, rlo, rhi);
        }
    };
    build_csr(uv_rows, uv_cols, uv_vals, N_USERS, 4, uv_off, uv_cur, uv_edg);
    build_csr(vu_rows, vu_cols, vu_vals, N_ITEMS, 4, vu_off, vu_cur, vu_edg);

    // dual SpMM: A = vu graph (items out), B = uv graph (users out)
    auto spmm_pair = [&](const _Float16* xu, _Float16* outI,
                         const _Float16* xv, _Float16* outU) {
        size_t groups = (size_t)N_ITEMS + N_USERS;
        int blocks = (int)((groups * 16 + 255) / 256);
        spmm_dual_kernel<<<blocks, 256, 0, stream>>>(
            vu_off, vu_edg, xu, outI, N_ITEMS,
            uv_off, uv_edg, xv, outU, N_USERS);
    };

    const int UB = (N_USERS + 127) / 128;   // user GEMM blocks
    const int IB = (N_ITEMS + 127) / 128;   // item GEMM blocks

    // ---------------- layer 0 (cur_u = Uf, cur_v = Vf) ----------------
    // in/out disjoint per launch: {Uf,Vf}->{Va,Ua}, {Ua,Va}->{Vb,Ub}
    spmm_pair(Uf, Va, Vf, Ua);        // TI -> Va [I],  TU -> Ua [U]
    spmm_pair(Ua, Vb, Va, Ub);        // HV -> Vb [I],  HU -> Ub [U]
    gemm_dual_kernel<0><<<UB + IB, 256, 0, stream>>>(
        Ub, Uf, Wt_user, user_b, (float*)nullptr, Ua, N_USERS, UB,
        Vb, Vf, Wt_item, item_b, (float*)nullptr, Va, N_ITEMS);
    // learn_user -> Ua, learn_item -> Va

    // ---------------- layer 1 (cur_u = Ua, cur_v = Va) -----------------
    // {Ua,Va}->{Vb,Ub}, then {Ub,Vb}->{Vc,Uc}: disjoint, no WAR race
    spmm_pair(Ua, Vb, Va, Ub);        // TI' -> Vb,  TU' -> Ub
    spmm_pair(Ub, Vc, Vb, Uc);        // HV' -> Vc,  HU' -> Uc
    gemm_dual_kernel<1><<<UB + IB, 256, 0, stream>>>(
        Uc, Ua, Wt_user + 32768, user_b + DIM, out_user, (_Float16*)nullptr, N_USERS, UB,
        Vc, Va, Wt_item + 32768, item_b + DIM, out_item, (_Float16*)nullptr, N_ITEMS);
}

// Round 9
// 1225.263 us; speedup vs baseline: 1.8302x; 1.0077x over previous
//
#include <hip/hip_runtime.h>

#define DIM 128
#define N_USERS 200000
#define N_ITEMS 100000

typedef __attribute__((ext_vector_type(8))) _Float16 half8;
typedef __attribute__((ext_vector_type(4))) _Float16 half4v;
typedef __attribute__((ext_vector_type(4))) float f32x4;

// ===========================================================================
// CSR build: dual histogram -> per-graph 3-phase scan -> dual windowed scatter
// ===========================================================================

__global__ __launch_bounds__(256) void hist_dual_kernel(
    const int* __restrict__ rowsA, int* __restrict__ cntA, int nA,
    const int* __restrict__ rowsB, int* __restrict__ cntB, int nB)
{
    int t = blockIdx.x * blockDim.x + threadIdx.x;
    if (t < nA) {
        atomicAdd(&cntA[rowsA[t]], 1);
    } else {
        t -= nA;
        if (t < nB) atomicAdd(&cntB[rowsB[t]], 1);
    }
}

__global__ __launch_bounds__(256) void scan1_kernel(
    const int* __restrict__ in, int* __restrict__ out,
    int* __restrict__ blockSums, int n)
{
    __shared__ int lds[256];
    int tid  = threadIdx.x;
    int base = blockIdx.x * 1024 + tid * 4;
    int v0 = (base + 0 < n) ? in[base + 0] : 0;
    int v1 = (base + 1 < n) ? in[base + 1] : 0;
    int v2 = (base + 2 < n) ? in[base + 2] : 0;
    int v3 = (base + 3 < n) ? in[base + 3] : 0;
    int s1 = v0 + v1, s2 = s1 + v2, s3 = s2 + v3;
    lds[tid] = s3;
    __syncthreads();
    for (int d = 1; d < 256; d <<= 1) {
        int t = 0;
        if (tid >= d) t = lds[tid - d];
        __syncthreads();
        lds[tid] += t;
        __syncthreads();
    }
    int excl = (tid > 0) ? lds[tid - 1] : 0;
    if (base + 0 < n) out[base + 1] = excl + v0;
    if (base + 1 < n) out[base + 2] = excl + s1;
    if (base + 2 < n) out[base + 3] = excl + s2;
    if (base + 3 < n) out[base + 4] = excl + s3;
    if (tid == 255) blockSums[blockIdx.x] = lds[255];
    if (blockIdx.x == 0 && tid == 0) out[0] = 0;
}

__global__ __launch_bounds__(256) void scan2_kernel(int* __restrict__ bs, int nb)
{
    __shared__ int lds[256];
    int tid  = threadIdx.x;
    int base = tid * 4;
    int v0 = (base + 0 < nb) ? bs[base + 0] : 0;
    int v1 = (base + 1 < nb) ? bs[base + 1] : 0;
    int v2 = (base + 2 < nb) ? bs[base + 2] : 0;
    int v3 = (base + 3 < nb) ? bs[base + 3] : 0;
    int s1 = v0 + v1, s2 = s1 + v2, s3 = s2 + v3;
    lds[tid] = s3;
    __syncthreads();
    for (int d = 1; d < 256; d <<= 1) {
        int t = 0;
        if (tid >= d) t = lds[tid - d];
        __syncthreads();
        lds[tid] += t;
        __syncthreads();
    }
    int run = (tid > 0) ? lds[tid - 1] : 0;
    if (base + 0 < nb) { int o = bs[base + 0]; bs[base + 0] = run; run += o; }
    if (base + 1 < nb) { int o = bs[base + 1]; bs[base + 1] = run; run += o; }
    if (base + 2 < nb) { int o = bs[base + 2]; bs[base + 2] = run; run += o; }
    if (base + 3 < nb) { int o = bs[base + 3]; bs[base + 3] = run; run += o; }
}

__global__ __launch_bounds__(256) void scan3_kernel(
    int* __restrict__ out, const int* __restrict__ bs, int n)
{
    int b = blockIdx.x;
    if (b == 0) return;
    int add  = bs[b];
    int base = b * 1024 + threadIdx.x * 4;
    if (base + 0 < n) out[base + 1] += add;
    if (base + 1 < n) out[base + 2] += add;
    if (base + 2 < n) out[base + 3] += add;
    if (base + 3 < n) out[base + 4] += add;
}

// Dual windowed scatter: graph A edges then graph B edges in one launch,
// each restricted to its own row window -> write sets stay L2-resident.
__global__ __launch_bounds__(256) void scatter_window_dual_kernel(
    const int* __restrict__ rowsA, const int* __restrict__ colsA,
    const float* __restrict__ valsA, int* __restrict__ curA,
    int2* __restrict__ edgA, int nA, int rloA, int rhiA,
    const int* __restrict__ rowsB, const int* __restrict__ colsB,
    const float* __restrict__ valsB, int* __restrict__ curB,
    int2* __restrict__ edgB, int nB, int rloB, int rhiB)
{
    int t = blockIdx.x * blockDim.x + threadIdx.x;
    if (t < nA) {
        int r = rowsA[t];
        if (r < rloA || r >= rhiA) return;
        int pos = atomicAdd(&curA[r], 1);
        edgA[pos] = make_int2(colsA[t], __float_as_int(valsA[t]));
    } else {
        t -= nA;
        if (t >= nB) return;
        int r = rowsB[t];
        if (r < rloB || r >= rhiB) return;
        int pos = atomicAdd(&curB[r], 1);
        edgB[pos] = make_int2(colsB[t], __float_as_int(valsB[t]));
    }
}

// ===========================================================================
// fp32 -> fp16 conversion for both feature tables in one launch
// ===========================================================================
__global__ __launch_bounds__(256) void conv_dual_kernel(
    const float* __restrict__ srcA, _Float16* __restrict__ dstA, int n8A,
    const float* __restrict__ srcB, _Float16* __restrict__ dstB, int n8B)
{
    int t = blockIdx.x * blockDim.x + threadIdx.x;
    const float* src;
    _Float16* dst;
    if (t < n8A) { src = srcA; dst = dstA; }
    else {
        t -= n8A;
        if (t >= n8B) return;
        src = srcB; dst = dstB;
    }
    const float4* s = reinterpret_cast<const float4*>(src) + (size_t)t * 2;
    float4 a = s[0], b = s[1];
    half8 h;
    h[0] = (_Float16)a.x; h[1] = (_Float16)a.y;
    h[2] = (_Float16)a.z; h[3] = (_Float16)a.w;
    h[4] = (_Float16)b.x; h[5] = (_Float16)b.y;
    h[6] = (_Float16)b.z; h[7] = (_Float16)b.w;
    reinterpret_cast<half8*>(dst)[t] = h;
}

// Both W tensors [2][256][128] fp32 -> Wt [2][128][256] fp16 in one launch
__global__ __launch_bounds__(256) void transposeW_dual_kernel(
    const float* __restrict__ Wu, _Float16* __restrict__ Wtu,
    const float* __restrict__ Wi, _Float16* __restrict__ Wti)
{
    int t = blockIdx.x * blockDim.x + threadIdx.x;   // 0..131071
    const float* W;
    _Float16* Wt;
    if (t < 65536) { W = Wu; Wt = Wtu; }
    else           { W = Wi; Wt = Wti; t -= 65536; }
    int l = t >> 15;
    int r = t & 32767;
    int k = r >> 7;
    int n = r & 127;
    Wt[(size_t)l * 32768 + n * 256 + k] = (_Float16)W[t];
}

// ===========================================================================
// Dual CSR SpMM fp16: 16 lanes/row, 16B gathers, 8-way unrolled (MLP),
// fp32 accum, fp16 store. Callers guarantee out does not alias x.
// ===========================================================================
__global__ __launch_bounds__(256) void spmm_dual_kernel(
    const int* __restrict__ offA, const int2* __restrict__ edgA,
    const _Float16* __restrict__ xA, _Float16* __restrict__ outA, int nA,
    const int* __restrict__ offB, const int2* __restrict__ edgB,
    const _Float16* __restrict__ xB, _Float16* __restrict__ outB, int nB)
{
    int t    = blockIdx.x * blockDim.x + threadIdx.x;
    int grp  = t >> 4;
    int lane = t & 15;

    const int*      off;
    const int2*     edg;
    const _Float16* x;
    _Float16*       out;
    int row;
    if (grp < nA) {
        off = offA; edg = edgA; x = xA; out = outA; row = grp;
    } else {
        row = grp - nA;
        if (row >= nB) return;
        off = offB; edg = edgB; x = xB; out = outB;
    }

    int beg = off[row], end = off[row + 1];
    float acc[8] = {0.f, 0.f, 0.f, 0.f, 0.f, 0.f, 0.f, 0.f};
    int k = beg;
    for (; k + 7 < end; k += 8) {
        int2 e[8];
        half8 xv[8];
#pragma unroll
        for (int u = 0; u < 8; ++u) e[u] = edg[k + u];
#pragma unroll
        for (int u = 0; u < 8; ++u)
            xv[u] = *reinterpret_cast<const half8*>(
                x + (size_t)e[u].x * DIM + lane * 8);
#pragma unroll
        for (int u = 0; u < 8; ++u) {
            float v = __int_as_float(e[u].y);
#pragma unroll
            for (int i = 0; i < 8; ++i) acc[i] += v * (float)xv[u][i];
        }
    }
    if (k + 3 < end) {
        int2 e[4];
        half8 xv[4];
#pragma unroll
        for (int u = 0; u < 4; ++u) e[u] = edg[k + u];
#pragma unroll
        for (int u = 0; u < 4; ++u)
            xv[u] = *reinterpret_cast<const half8*>(
                x + (size_t)e[u].x * DIM + lane * 8);
#pragma unroll
        for (int u = 0; u < 4; ++u) {
            float v = __int_as_float(e[u].y);
#pragma unroll
            for (int i = 0; i < 8; ++i) acc[i] += v * (float)xv[u][i];
        }
        k += 4;
    }
    for (; k < end; ++k) {
        int2 e0 = edg[k];
        half8 x0 = *reinterpret_cast<const half8*>(x + (size_t)e0.x * DIM + lane * 8);
        float v0 = __int_as_float(e0.y);
#pragma unroll
        for (int i = 0; i < 8; ++i) acc[i] += v0 * (float)x0[i];
    }
    half8 o;
#pragma unroll
    for (int i = 0; i < 8; ++i) o[i] = (_Float16)acc[i];
    *reinterpret_cast<half8*>(out + (size_t)row * DIM + lane * 8) = o;
}

// ===========================================================================
// Dual MFMA GEMM, W-in-registers: user blocks [0, ublocks), item blocks rest.
// 4 waves/block; wave w owns output features [w*32, w*32+32).
// W frags (64 VGPR) + bias hoisted; per 16-row tile only 8 A loads + 16 MFMA.
// ===========================================================================
template<int OUT_F32>
__global__ __launch_bounds__(256) void gemm_dual_kernel(
    const _Float16* __restrict__ HOu, const _Float16* __restrict__ CURu,
    const _Float16* __restrict__ Wtu, const float* __restrict__ bu,
    float* __restrict__ outFu, _Float16* __restrict__ outHu, int Mu, int ublocks,
    const _Float16* __restrict__ HOi, const _Float16* __restrict__ CURi,
    const _Float16* __restrict__ Wti, const float* __restrict__ bi,
    float* __restrict__ outFi, _Float16* __restrict__ outHi, int Mi)
{
    const int TILES = 8;
    int bid = blockIdx.x;
    const _Float16 *HO, *CUR, *Wt;
    const float* bias;
    float* outF;
    _Float16* outH;
    int M;
    if (bid < ublocks) {
        HO = HOu; CUR = CURu; Wt = Wtu; bias = bu; outF = outFu; outH = outHu; M = Mu;
    } else {
        bid -= ublocks;
        HO = HOi; CUR = CURi; Wt = Wti; bias = bi; outF = outFi; outH = outHi; M = Mi;
    }

    int tid  = threadIdx.x;
    int wave = tid >> 6;
    int l    = tid & 63;
    int m    = l & 15;
    int kg   = l >> 4;

    half8 wfrag[2][8];
    float4 bv[2];
#pragma unroll
    for (int jj = 0; jj < 2; ++jj) {
        int j = wave * 2 + jj;
#pragma unroll
        for (int kk = 0; kk < 8; ++kk)
            wfrag[jj][kk] = *reinterpret_cast<const half8*>(
                Wt + (size_t)(j * 16 + m) * 256 + kk * 32 + kg * 8);
        bv[jj] = *reinterpret_cast<const float4*>(bias + j * 16 + kg * 4);
    }

    int base = bid * (TILES * 16);
#pragma unroll 2
    for (int t = 0; t < TILES; ++t) {
        int row = base + t * 16 + m;
        int rr  = min(row, M - 1);
        half8 afrag[8];
#pragma unroll
        for (int kk = 0; kk < 8; ++kk) {
            const _Float16* src = (kk < 4) ? HO : CUR;
            int k0 = (kk & 3) * 32 + kg * 8;
            afrag[kk] = *reinterpret_cast<const half8*>(src + (size_t)rr * DIM + k0);
        }
#pragma unroll
        for (int jj = 0; jj < 2; ++jj) {
            f32x4 acc = {0.f, 0.f, 0.f, 0.f};
#pragma unroll
            for (int kk = 0; kk < 8; ++kk)
                acc = __builtin_amdgcn_mfma_f32_16x16x32_f16(
                    wfrag[jj][kk], afrag[kk], acc, 0, 0, 0);
            int n0 = (wave * 2 + jj) * 16 + kg * 4;
            float o0 = fmaxf(acc[0] + bv[jj].x, 0.f);
            float o1 = fmaxf(acc[1] + bv[jj].y, 0.f);
            float o2 = fmaxf(acc[2] + bv[jj].z, 0.f);
            float o3 = fmaxf(acc[3] + bv[jj].w, 0.f);
            if (row < M) {
                if (OUT_F32) {
                    float4 st = make_float4(o0, o1, o2, o3);
                    *reinterpret_cast<float4*>(outF + (size_t)row * DIM + n0) = st;
                } else {
                    half4v st;
                    st[0] = (_Float16)o0; st[1] = (_Float16)o1;
                    st[2] = (_Float16)o2; st[3] = (_Float16)o3;
                    *reinterpret_cast<half4v*>(outH + (size_t)row * DIM + n0) = st;
                }
            }
        }
    }
}

extern "C" void kernel_launch(void* const* d_in, const int* in_sizes, int n_in,
                              void* d_out, int out_size, void* d_ws, size_t ws_size,
                              hipStream_t stream) {
    const float* ufea    = (const float*)d_in[0];
    const float* vfea    = (const float*)d_in[1];
    const int*   uv_rows = (const int*)d_in[2];
    const int*   uv_cols = (const int*)d_in[3];
    const float* uv_vals = (const float*)d_in[4];
    const int*   vu_rows = (const int*)d_in[5];
    const int*   vu_cols = (const int*)d_in[6];
    const float* vu_vals = (const float*)d_in[7];
    const float* user_W  = (const float*)d_in[8];
    const float* user_b  = (const float*)d_in[9];
    const float* item_W  = (const float*)d_in[10];
    const float* item_b  = (const float*)d_in[11];

    const int nnz = in_sizes[2];

    float* out_user = (float*)d_out;
    float* out_item = out_user + (size_t)N_USERS * DIM;

    const size_t UD = (size_t)N_USERS * DIM;
    const size_t ID = (size_t)N_ITEMS * DIM;

    char* p = (char*)d_ws;
    auto alloc = [&](size_t bytes) {
        char* q = p;
        p += (bytes + 255) & ~(size_t)255;
        return q;
    };
    _Float16* Uf = (_Float16*)alloc(UD * 2);
    _Float16* Vf = (_Float16*)alloc(ID * 2);
    _Float16* Ua = (_Float16*)alloc(UD * 2);
    _Float16* Ub = (_Float16*)alloc(UD * 2);
    _Float16* Uc = (_Float16*)alloc(UD * 2);   // breaks layer-1 WAR alias
    _Float16* Va = (_Float16*)alloc(ID * 2);
    _Float16* Vb = (_Float16*)alloc(ID * 2);
    _Float16* Vc = (_Float16*)alloc(ID * 2);
    _Float16* Wt_user = (_Float16*)alloc((size_t)2 * 128 * 256 * 2);
    _Float16* Wt_item = (_Float16*)alloc((size_t)2 * 128 * 256 * 2);
    int*  uv_off = (int*)alloc((N_USERS + 1) * 4);
    int*  uv_cur = (int*)alloc((N_USERS + 1) * 4);
    int2* uv_edg = (int2*)alloc((size_t)nnz * 8);
    int*  vu_off = (int*)alloc((N_ITEMS + 1) * 4);
    int*  vu_cur = (int*)alloc((N_ITEMS + 1) * 4);
    int2* vu_edg = (int2*)alloc((size_t)nnz * 8);
    int*  bsums  = (int*)alloc(1024 * 4);

    // ---- prep: fp16 feature tables + transposed fp16 weights ----
    {
        int n8A = (int)(UD / 8), n8B = (int)(ID / 8);
        conv_dual_kernel<<<(n8A + n8B + 255) / 256, 256, 0, stream>>>(
            ufea, Uf, n8A, vfea, Vf, n8B);
        transposeW_dual_kernel<<<512, 256, 0, stream>>>(user_W, Wt_user,
                                                        item_W, Wt_item);
    }

    // ---- CSR build for both graphs (dual launches) ----
    {
        int eb2 = (2 * nnz + 255) / 256;
        hipMemsetAsync(uv_cur, 0, (size_t)(N_USERS + 1) * 4, stream);
        hipMemsetAsync(vu_cur, 0, (size_t)(N_ITEMS + 1) * 4, stream);
        hist_dual_kernel<<<eb2, 256, 0, stream>>>(uv_rows, uv_cur, nnz,
                                                  vu_rows, vu_cur, nnz);
        int nbU = (N_USERS + 1023) / 1024;
        int nbI = (N_ITEMS + 1023) / 1024;
        scan1_kernel<<<nbU, 256, 0, stream>>>(uv_cur, uv_off, bsums, N_USERS);
        scan2_kernel<<<1, 256, 0, stream>>>(bsums, nbU);
        scan3_kernel<<<nbU, 256, 0, stream>>>(uv_off, bsums, N_USERS);
        scan1_kernel<<<nbI, 256, 0, stream>>>(vu_cur, vu_off, bsums, N_ITEMS);
        scan2_kernel<<<1, 256, 0, stream>>>(bsums, nbI);
        scan3_kernel<<<nbI, 256, 0, stream>>>(vu_off, bsums, N_ITEMS);
        hipMemcpyAsync(uv_cur, uv_off, (size_t)N_USERS * 4,
                       hipMemcpyDeviceToDevice, stream);
        hipMemcpyAsync(vu_cur, vu_off, (size_t)N_ITEMS * 4,
                       hipMemcpyDeviceToDevice, stream);
        const int NPASS = 4;
        int wU = (N_USERS + NPASS - 1) / NPASS;
        int wI = (N_ITEMS + NPASS - 1) / NPASS;
        for (int pass = 0; pass < NPASS; ++pass) {
            scatter_window_dual_kernel<<<eb2, 256, 0, stream>>>(
                uv_rows, uv_cols, uv_vals, uv_cur, uv_edg, nnz,
                pass * wU, min((pass + 1) * wU, N_USERS),
                vu_rows, vu_cols, vu_vals, vu_cur, vu_edg, nnz,
                pass * wI, min((pass + 1) * wI, N_ITEMS));
        }
    }

    // dual SpMM: A = vu graph (items out), B = uv graph (users out)
    auto spmm_pair = [&](const _Float16* xu, _Float16* outI,
                         const _Float16* xv, _Float16* outU) {
        size_t groups = (size_t)N_ITEMS + N_USERS;
        int blocks = (int)((groups * 16 + 255) / 256);
        spmm_dual_kernel<<<blocks, 256, 0, stream>>>(
            vu_off, vu_edg, xu, outI, N_ITEMS,
            uv_off, uv_edg, xv, outU, N_USERS);
    };

    const int UB = (N_USERS + 127) / 128;
    const int IB = (N_ITEMS + 127) / 128;

    // ---------------- layer 0 (cur_u = Uf, cur_v = Vf) ----------------
    // in/out disjoint per launch: {Uf,Vf}->{Va,Ua}, {Ua,Va}->{Vb,Ub}
    spmm_pair(Uf, Va, Vf, Ua);        // TI -> Va [I],  TU -> Ua [U]
    spmm_pair(Ua, Vb, Va, Ub);        // HV -> Vb [I],  HU -> Ub [U]
    gemm_dual_kernel<0><<<UB + IB, 256, 0, stream>>>(
        Ub, Uf, Wt_user, user_b, (float*)nullptr, Ua, N_USERS, UB,
        Vb, Vf, Wt_item, item_b, (float*)nullptr, Va, N_ITEMS);
    // learn_user -> Ua, learn_item -> Va

    // ---------------- layer 1 (cur_u = Ua, cur_v = Va) -----------------
    // {Ua,Va}->{Vb,Ub}, then {Ub,Vb}->{Vc,Uc}: disjoint, no WAR race
    spmm_pair(Ua, Vb, Va, Ub);        // TI' -> Vb,  TU' -> Ub
    spmm_pair(Ub, Vc, Vb, Uc);        // HV' -> Vc,  HU' -> Uc
    gemm_dual_kernel<1><<<UB + IB, 256, 0, stream>>>(
        Uc, Ua, Wt_user + 32768, user_b + DIM, out_user, (_Float16*)nullptr, N_USERS, UB,
        Vc, Va, Wt_item + 32768, item_b + DIM, out_item, (_Float16*)nullptr, N_ITEMS);
}